// Round 11
// baseline (517.728 us; speedup 1.0000x reference)
//
#include <hip/hip_runtime.h>

// GAT node regressor: 3 GAT layers (HID=64, 4 heads x 16) + linear head.
// CSR-by-dst built once per call via bucketed counting sort. Per layer:
//   k_gemm0/k_gemm12: xh = h@W; 256-thread block, 64-node tile, thread tile
//           2 nodes x 8 cols (issue-balanced: 2 b128 DS + 8 L1-W dwordx4 per
//           64 FMA). h in LDS (D64: 17KB -> 8 blocks/CU; D128: 34KB -> 4),
//           W via VMEM L1 (same 16-32KB for all blocks); unroll capped
//           (full unroll = VGPR-256 trap, R6; 1-wave block = LDS-occupancy
//           trap, R10). Fused al_s/al_d head logits.
//   k_edge: per-edge softmax numerators pe[j][h] (coalesced, edge-parallel)
//   k_agg : wave-per-dst-node gather (R7-proven): chunk stash of (u, pe4) in
//           head-transposed LDS, broadcast b128 pair + 4 row gathers per group.
//           Layer 2 fuses h@out_w via shuffle.

#define NBMAX 512   // max dst buckets (dst>>8); N=100K -> 391
#define SCHUNK 4096 // edges per k_bscatter block
#define BCAP 8192   // per-bucket LDS src capacity in k_bfinal (avg 4096)

__global__ __launch_bounds__(256) void k_zero(int* p, int n) {
    int i = blockIdx.x * 256 + threadIdx.x;
    if (i < n) p[i] = 0;
}

__global__ __launch_bounds__(256) void k_bhist(const int* __restrict__ dst, int* __restrict__ bhist, int e) {
    __shared__ unsigned int h[NBMAX];
    int t = threadIdx.x;
    h[t] = 0;
    h[t + 256] = 0;
    __syncthreads();
    for (int i = blockIdx.x * 256 + t; i < e; i += gridDim.x * 256)
        atomicAdd(&h[dst[i] >> 8], 1u);
    __syncthreads();
    if (h[t]) atomicAdd(&bhist[t], (int)h[t]);
    if (h[t + 256]) atomicAdd(&bhist[t + 256], (int)h[t + 256]);
}

__global__ __launch_bounds__(512) void k_bscan(const int* __restrict__ bhist, int* __restrict__ boffs,
                                               int* __restrict__ bfill, int nb, int e) {
    __shared__ int s[NBMAX];
    int t = threadIdx.x;
    int v = (t < nb) ? bhist[t] : 0;
    s[t] = v;
    __syncthreads();
    for (int o = 1; o < 512; o <<= 1) {
        int add = (t >= o) ? s[t - o] : 0;
        __syncthreads();
        s[t] += add;
        __syncthreads();
    }
    boffs[t] = s[t] - v;  // exclusive
    if (t == 511) boffs[512] = s[511];
    bfill[t] = 0;
}

// Block-local counting sort of a 4096-edge chunk by dst>>8, then streamed
// writes of sorted runs. Packs src (17b) | (dst&255)<<24 into 4B.
__global__ __launch_bounds__(512) void k_bscatter(const int* __restrict__ src, const int* __restrict__ dst,
                                                  const int* __restrict__ boffs, int* __restrict__ bfill,
                                                  unsigned int* __restrict__ edata, int e) {
    __shared__ unsigned int hist[NBMAX];   // counts, then cursor
    __shared__ unsigned int loc[NBMAX];    // local exclusive offsets
    __shared__ int gbase[NBMAX];
    __shared__ unsigned int stmp[NBMAX];
    __shared__ unsigned int sortbuf[SCHUNK];
    __shared__ int posbuf[SCHUNK];
    int t = threadIdx.x;
    int i0 = blockIdx.x * SCHUNK;
    int cnt = min(SCHUNK, e - i0);
    hist[t] = 0;
    __syncthreads();
    for (int j = t; j < cnt; j += 512) atomicAdd(&hist[dst[i0 + j] >> 8], 1u);
    __syncthreads();
    unsigned int v = hist[t];
    stmp[t] = v;
    __syncthreads();
    for (int o = 1; o < 512; o <<= 1) {
        unsigned int add = (t >= o) ? stmp[t - o] : 0;
        __syncthreads();
        stmp[t] += add;
        __syncthreads();
    }
    loc[t] = stmp[t] - v;
    int gb = 0;
    if (v > 0) gb = atomicAdd(&bfill[t], (int)v);  // reserve contiguous run in bucket t
    gbase[t] = boffs[t] + gb - (int)loc[t];
    hist[t] = loc[t];  // cursor
    __syncthreads();
    for (int j = t; j < cnt; j += 512) {
        int d = dst[i0 + j];
        int s = src[i0 + j];
        int b = d >> 8;
        unsigned int p = atomicAdd(&hist[b], 1u);
        sortbuf[p] = (unsigned int)s | ((unsigned int)(d & 255) << 24);
        posbuf[p] = gbase[b] + (int)p;
    }
    __syncthreads();
    for (int j = t; j < cnt; j += 512) edata[posbuf[j]] = sortbuf[j];
}

// One block per bucket: 256-bin counting sort by local dst; coalesced output
// of offs, ssrc (sorted srcs) and sdst (sorted dsts, for k_edge).
__global__ __launch_bounds__(256) void k_bfinal(const unsigned int* __restrict__ edata,
                                                const int* __restrict__ boffs, int* __restrict__ offs,
                                                int* __restrict__ ssrc, int* __restrict__ sdst,
                                                int n, int nb) {
    __shared__ unsigned int hist[256];
    __shared__ unsigned int stmp[256];
    __shared__ unsigned int loc[256];
    __shared__ unsigned int srcbuf[BCAP];
    __shared__ unsigned char dstbuf[BCAP];
    int b = blockIdx.x;
    int t = threadIdx.x;
    int e0 = boffs[b], e1 = boffs[b + 1];
    int cnt = e1 - e0;
    hist[t] = 0;
    __syncthreads();
    for (int j = t; j < cnt; j += 256) atomicAdd(&hist[edata[e0 + j] >> 24], 1u);
    __syncthreads();
    unsigned int v = hist[t];
    stmp[t] = v;
    __syncthreads();
    for (int o = 1; o < 256; o <<= 1) {
        unsigned int add = (t >= o) ? stmp[t - o] : 0;
        __syncthreads();
        stmp[t] += add;
        __syncthreads();
    }
    loc[t] = stmp[t] - v;
    int node = b * 256 + t;
    if (node < n) offs[node] = e0 + (int)loc[t];
    if (b == nb - 1 && t == 0) offs[n] = e1;
    hist[t] = loc[t];  // cursor
    __syncthreads();
    if (cnt <= BCAP) {
        for (int j = t; j < cnt; j += 256) {
            unsigned int p = edata[e0 + j];
            unsigned int pos = atomicAdd(&hist[p >> 24], 1u);
            srcbuf[pos] = p & 0xFFFFFFu;
            dstbuf[pos] = (unsigned char)(p >> 24);
        }
        __syncthreads();
        for (int j = t; j < cnt; j += 256) {
            ssrc[e0 + j] = (int)srcbuf[j];
            sdst[e0 + j] = b * 256 + (int)dstbuf[j];
        }
    } else {  // safety fallback (never hit for Poisson(4096) buckets)
        for (int j = t; j < cnt; j += 256) {
            unsigned int p = edata[e0 + j];
            unsigned int pos = atomicAdd(&hist[p >> 24], 1u);
            ssrc[e0 + (int)pos] = (int)(p & 0xFFFFFFu);
            sdst[e0 + (int)pos] = b * 256 + (int)(p >> 24);
        }
    }
}

// xh = h @ W  (h: [n, D_IN], W: [D_IN, 64]) fused with per-head logits.
// 256-thread block, 64-node tile. Thread: w=t>>6, ng=(t>>3)&7, cg=t&7;
// computes nodes {w*16 + j*8 + ng, j=0,1} x cols cg*8..+7.
// h in LDS, HSTR = D_IN+4 == 4 (mod 32): at fixed j the 8 ng-rows hit bank
// quads 0,4,..,28 -> conflict-free b128 with 8-fold cg broadcast.
// W via VMEM: 8 distinct addrs/wave-instr (duplicate-coalesced), L1-resident.
template <int D_IN>
__device__ __forceinline__ void gemm_body(const float* __restrict__ h, const float* __restrict__ W,
                                          const float* __restrict__ asrc, const float* __restrict__ adst,
                                          float* __restrict__ xh, float* __restrict__ als,
                                          float* __restrict__ ald, int n) {
    constexpr int HSTR = D_IN + 4;
    __shared__ float hlds[64 * HSTR];
    int t = threadIdx.x;
    int node0 = blockIdx.x * 64;
    constexpr int HTOT = 16 * D_IN;  // float4 count for 64 rows
    for (int i = t; i < HTOT; i += 256) {
        int f = i * 4;
        int nd = f / D_IN, k = f % D_IN;
        float4 val = make_float4(0.f, 0.f, 0.f, 0.f);
        if (node0 + nd < n) val = *(const float4*)(h + (size_t)(node0 + nd) * D_IN + k);
        *(float4*)(hlds + nd * HSTR + k) = val;
    }
    __syncthreads();
    int w = t >> 6, ng = (t >> 3) & 7, cg = t & 7;
    int nbase = w * 16 + ng;  // + j*8
    float4 acc[2][2];
#pragma unroll
    for (int j = 0; j < 2; ++j) {
        acc[j][0] = make_float4(0.f, 0.f, 0.f, 0.f);
        acc[j][1] = make_float4(0.f, 0.f, 0.f, 0.f);
    }
#pragma unroll 2
    for (int k = 0; k < D_IN; k += 4) {
        float4 wv[4][2];
#pragma unroll
        for (int kk = 0; kk < 4; ++kk) {
            wv[kk][0] = *(const float4*)(W + (size_t)(k + kk) * 64 + cg * 8);      // L1 hit
            wv[kk][1] = *(const float4*)(W + (size_t)(k + kk) * 64 + cg * 8 + 4);
        }
#pragma unroll
        for (int j = 0; j < 2; ++j) {
            float4 hv = *(const float4*)(hlds + (nbase + j * 8) * HSTR + k);  // broadcast x8
#pragma unroll
            for (int c = 0; c < 2; ++c) {
                acc[j][c].x += hv.x * wv[0][c].x + hv.y * wv[1][c].x + hv.z * wv[2][c].x + hv.w * wv[3][c].x;
                acc[j][c].y += hv.x * wv[0][c].y + hv.y * wv[1][c].y + hv.z * wv[2][c].y + hv.w * wv[3][c].y;
                acc[j][c].z += hv.x * wv[0][c].z + hv.y * wv[1][c].z + hv.z * wv[2][c].z + hv.w * wv[3][c].z;
                acc[j][c].w += hv.x * wv[0][c].w + hv.y * wv[1][c].w + hv.z * wv[2][c].w + hv.w * wv[3][c].w;
            }
        }
    }
    // epilogue: logits. cols cg*8..+7 lie in head = cg>>1, half (cg&1).
    int head = cg >> 1;
    const float* asp = asrc + head * 16 + (cg & 1) * 8;
    const float* adp = adst + head * 16 + (cg & 1) * 8;
    float4 as0 = *(const float4*)(asp), as1 = *(const float4*)(asp + 4);
    float4 ad0 = *(const float4*)(adp), ad1 = *(const float4*)(adp + 4);
#pragma unroll
    for (int j = 0; j < 2; ++j) {
        int node = node0 + nbase + j * 8;
        float ps = acc[j][0].x * as0.x + acc[j][0].y * as0.y + acc[j][0].z * as0.z + acc[j][0].w * as0.w
                 + acc[j][1].x * as1.x + acc[j][1].y * as1.y + acc[j][1].z * as1.z + acc[j][1].w * as1.w;
        float pd = acc[j][0].x * ad0.x + acc[j][0].y * ad0.y + acc[j][0].z * ad0.z + acc[j][0].w * ad0.w
                 + acc[j][1].x * ad1.x + acc[j][1].y * ad1.y + acc[j][1].z * ad1.z + acc[j][1].w * ad1.w;
        ps += __shfl_xor(ps, 1, 64);  // partner col-half of same head (lane bit0 = cg bit0)
        pd += __shfl_xor(pd, 1, 64);
        if (node < n) {
            *(float4*)(xh + (size_t)node * 64 + cg * 8) = acc[j][0];
            *(float4*)(xh + (size_t)node * 64 + cg * 8 + 4) = acc[j][1];
            if ((cg & 1) == 0) {
                als[node * 4 + head] = ps;
                ald[node * 4 + head] = pd;
            }
        }
    }
}

__global__ __launch_bounds__(256) void k_gemm0(const float* __restrict__ h, const float* __restrict__ W,
                                               const float* __restrict__ asrc, const float* __restrict__ adst,
                                               float* __restrict__ xh, float* __restrict__ als,
                                               float* __restrict__ ald, int n) {
    gemm_body<128>(h, W, asrc, adst, xh, als, ald, n);
}

__global__ __launch_bounds__(256) void k_gemm12(const float* __restrict__ h, const float* __restrict__ W,
                                                const float* __restrict__ asrc, const float* __restrict__ adst,
                                                float* __restrict__ xh, float* __restrict__ als,
                                                float* __restrict__ ald, int n) {
    gemm_body<64>(h, W, asrc, adst, xh, als, ald, n);
}

__device__ inline float4 lrelu4(float4 v) {
    float4 r;
    r.x = v.x >= 0.f ? v.x : 0.2f * v.x;
    r.y = v.y >= 0.f ? v.y : 0.2f * v.y;
    r.z = v.z >= 0.f ? v.z : 0.2f * v.z;
    r.w = v.w >= 0.f ? v.w : 0.2f * v.w;
    return r;
}

// Edge-parallel softmax numerators: pe[j][h] = exp(lrelu(als[u]+ald[d]) - m[d]),
// m[d] = lrelu(als[d]+ald[d]) (self-logit as per-head shift; single pass,
// algebraically identical to ref's max-subtraction).
__global__ __launch_bounds__(256) void k_edge(const int* __restrict__ ssrc, const int* __restrict__ sdst,
                                              const float* __restrict__ als, const float* __restrict__ ald,
                                              float* __restrict__ pei, int e) {
    int j = blockIdx.x * 256 + threadIdx.x;
    if (j >= e) return;
    int u = ssrc[j], d = sdst[j];
    float4 alu = *(const float4*)(als + 4 * (size_t)u);
    float4 asd = *(const float4*)(als + 4 * (size_t)d);
    float4 add4 = *(const float4*)(ald + 4 * (size_t)d);
    float4 m4 = lrelu4(make_float4(asd.x + add4.x, asd.y + add4.y, asd.z + add4.z, asd.w + add4.w));
    float4 e4 = lrelu4(make_float4(alu.x + add4.x, alu.y + add4.y, alu.z + add4.z, alu.w + add4.w));
    float4 pe;
    pe.x = __expf(e4.x - m4.x);
    pe.y = __expf(e4.y - m4.y);
    pe.z = __expf(e4.z - m4.z);
    pe.w = __expf(e4.w - m4.w);
    *(float4*)(pei + 4 * (size_t)j) = pe;
}

// One wave per destination node; lane = feature column (head = lane>>4).
// Chunk phase: lane=edge loads (u, pe4) coalesced; stash u as row BYTE offset
// and pe transposed [head][edge] in LDS (all 64 lanes write; pad u=v, pe=0).
// Accumulate: per 4 edges, 2x broadcast ds_read_b128 + 4 row gathers + fmacs;
// z accumulated redundantly per lane (no end shuffle-reduce).
__global__ __launch_bounds__(256) void k_agg(const float* __restrict__ xh, const float* __restrict__ pei,
                                             const int* __restrict__ offs, const int* __restrict__ ssrc,
                                             const float* __restrict__ bias, float* __restrict__ hout,
                                             const float* __restrict__ outw, const float* __restrict__ outb,
                                             float* __restrict__ fout, int n) {
    __shared__ int s_u[4][64];
    __shared__ float s_pe[4][4][64];  // [wslot][head][edge]
    int wslot = threadIdx.x >> 6;
    int lane = threadIdx.x & 63;
    int v = (blockIdx.x * 256 + threadIdx.x) >> 6;
    if (v >= n) return;
    int head = lane >> 4;
    int* ub = s_u[wslot];
    float* per = s_pe[wslot][head];      // read row for my head
    float* pew = &s_pe[wslot][0][lane];  // write base, stride 64 per head

    int start = offs[v], end = offs[v + 1];
    const char* xl = (const char*)(xh + lane);      // lane column folded into base
    float acc = *(const float*)(xl + ((size_t)(unsigned)v << 8));  // self, pe=1
    float zsum = 0.f;

    for (int s0 = start; s0 < end; s0 += 64) {
        int cnt = min(64, end - s0);
        bool act = lane < cnt;
        int u = v;
        float4 pe = make_float4(0.f, 0.f, 0.f, 0.f);
        if (act) {
            u = ssrc[s0 + lane];
            pe = *(const float4*)(pei + 4 * (size_t)(s0 + lane));
        }
        ub[lane] = u << 8;   // row byte offset; pad lanes point at v (pe=0)
        pew[0] = pe.x;       // transposed stash: bank stride 64 -> 2-way, free
        pew[64] = pe.y;
        pew[128] = pe.z;
        pew[192] = pe.w;
        // same-wave LDS RAW (in-order DS unit), no barrier needed
        int ng = (cnt + 3) >> 2;
        int g = 0;
        for (; g + 2 <= ng; g += 2) {
            int4 uu0 = *(const int4*)&ub[g * 4];
            int4 uu1 = *(const int4*)&ub[g * 4 + 4];
            float4 pp0 = *(const float4*)&per[g * 4];
            float4 pp1 = *(const float4*)&per[g * 4 + 4];
            float x0 = *(const float*)(xl + (size_t)(unsigned)uu0.x);
            float x1 = *(const float*)(xl + (size_t)(unsigned)uu0.y);
            float x2 = *(const float*)(xl + (size_t)(unsigned)uu0.z);
            float x3 = *(const float*)(xl + (size_t)(unsigned)uu0.w);
            float x4 = *(const float*)(xl + (size_t)(unsigned)uu1.x);
            float x5 = *(const float*)(xl + (size_t)(unsigned)uu1.y);
            float x6 = *(const float*)(xl + (size_t)(unsigned)uu1.z);
            float x7 = *(const float*)(xl + (size_t)(unsigned)uu1.w);
            zsum += pp0.x + pp0.y + pp0.z + pp0.w;
            zsum += pp1.x + pp1.y + pp1.z + pp1.w;
            acc += pp0.x * x0; acc += pp0.y * x1; acc += pp0.z * x2; acc += pp0.w * x3;
            acc += pp1.x * x4; acc += pp1.y * x5; acc += pp1.z * x6; acc += pp1.w * x7;
        }
        for (; g < ng; ++g) {
            int4 uu = *(const int4*)&ub[g * 4];
            float4 pp = *(const float4*)&per[g * 4];
            float x0 = *(const float*)(xl + (size_t)(unsigned)uu.x);
            float x1 = *(const float*)(xl + (size_t)(unsigned)uu.y);
            float x2 = *(const float*)(xl + (size_t)(unsigned)uu.z);
            float x3 = *(const float*)(xl + (size_t)(unsigned)uu.w);
            zsum += pp.x + pp.y + pp.z + pp.w;
            acc += pp.x * x0; acc += pp.y * x1; acc += pp.z * x2; acc += pp.w * x3;
        }
    }
    float z = 1.f + zsum;  // +1 = self edge
    float o = acc / (z + 1e-16f) + bias[lane];
    o = fmaxf(o, 0.f);
    if (outw) {
        float tsum = o * outw[lane];
#pragma unroll
        for (int d = 32; d; d >>= 1) tsum += __shfl_down(tsum, d, 64);
        if (lane == 0) fout[v] = tsum + outb[0];
    } else {
        hout[((size_t)v << 6) + lane] = o;
    }
}

extern "C" void kernel_launch(void* const* d_in, const int* in_sizes, int n_in,
                              void* d_out, int out_size, void* d_ws, size_t ws_size,
                              hipStream_t stream) {
    const float* x = (const float*)d_in[0];
    const int* ei = (const int*)d_in[1];
    const float* w[3] = {(const float*)d_in[2], (const float*)d_in[6], (const float*)d_in[10]};
    const float* as[3] = {(const float*)d_in[3], (const float*)d_in[7], (const float*)d_in[11]};
    const float* ad[3] = {(const float*)d_in[4], (const float*)d_in[8], (const float*)d_in[12]};
    const float* b[3] = {(const float*)d_in[5], (const float*)d_in[9], (const float*)d_in[13]};
    const float* outw = (const float*)d_in[14];
    const float* outb = (const float*)d_in[15];

    const int N = in_sizes[0] / 128;
    const int E = in_sizes[1] / 2;
    const int* src = ei;
    const int* dst = ei + E;
    const int NB = (N + 255) / 256;  // 391 <= NBMAX

    char* ws = (char*)d_ws;
    auto alloc = [&](size_t bytes) -> void* {
        void* p = (void*)ws;
        ws += (bytes + 255) & ~(size_t)255;
        return p;
    };
    int* bhist = (int*)alloc(NBMAX * 4);
    int* boffs = (int*)alloc((NBMAX + 1) * 4);
    int* bfill = (int*)alloc(NBMAX * 4);
    int* offs = (int*)alloc((size_t)(N + 1) * 4);
    int* ssrc = (int*)alloc((size_t)E * 4);
    int* sdst = (int*)alloc((size_t)E * 4);
    float* pei = (float*)alloc((size_t)E * 4 * 4);
    float* xh = (float*)alloc((size_t)N * 64 * 4);
    float* hbuf = (float*)alloc((size_t)N * 64 * 4);
    float* als = (float*)alloc((size_t)N * 4 * 4);
    float* ald = (float*)alloc((size_t)N * 4 * 4);
    // edata (E*4B) aliases xh (N*256B): dead before the first k_gemm writes xh.
    unsigned int* edata = (unsigned int*)xh;

    k_zero<<<(NBMAX + 255) / 256, 256, 0, stream>>>(bhist, NBMAX);
    k_bhist<<<256, 256, 0, stream>>>(dst, bhist, E);
    k_bscan<<<1, 512, 0, stream>>>(bhist, boffs, bfill, NB, E);
    k_bscatter<<<(E + SCHUNK - 1) / SCHUNK, 512, 0, stream>>>(src, dst, boffs, bfill, edata, E);
    k_bfinal<<<NB, 256, 0, stream>>>(edata, boffs, offs, ssrc, sdst, N, NB);

    const int gblocks = (N + 63) / 64;
    const int ablocks = (N + 3) / 4;
    const int eblocks = (E + 255) / 256;

    k_gemm0<<<gblocks, 256, 0, stream>>>(x, w[0], as[0], ad[0], xh, als, ald, N);
    k_edge<<<eblocks, 256, 0, stream>>>(ssrc, sdst, als, ald, pei, E);
    k_agg<<<ablocks, 256, 0, stream>>>(xh, pei, offs, ssrc, b[0], hbuf, nullptr, nullptr, nullptr, N);
    k_gemm12<<<gblocks, 256, 0, stream>>>(hbuf, w[1], as[1], ad[1], xh, als, ald, N);
    k_edge<<<eblocks, 256, 0, stream>>>(ssrc, sdst, als, ald, pei, E);
    k_agg<<<ablocks, 256, 0, stream>>>(xh, pei, offs, ssrc, b[1], hbuf, nullptr, nullptr, nullptr, N);
    k_gemm12<<<gblocks, 256, 0, stream>>>(hbuf, w[2], as[2], ad[2], xh, als, ald, N);
    k_edge<<<eblocks, 256, 0, stream>>>(ssrc, sdst, als, ald, pei, E);
    k_agg<<<ablocks, 256, 0, stream>>>(xh, pei, offs, ssrc, b[2], nullptr, outw, outb, (float*)d_out, N);
}

// Round 12
// 448.195 us; speedup vs baseline: 1.1551x; 1.1551x over previous
//
#include <hip/hip_runtime.h>

// GAT node regressor: 3 GAT layers (HID=64, 4 heads x 16) + linear head.
// CSR-by-dst built once per call via bucketed counting sort. Per layer:
//   k_mgemm: xh = h@W on MATRIX CORES via bf16 hi/lo split (fp32 emulation:
//            hh*wh + hh*wl + lo*wh, fp32 MFMA accumulate; dropped term ~2^-16).
//            Wave = 16 nodes x 64 cols, K-step 32, no LDS; W pre-packed into
//            B-fragment order by k_wprep (L1-resident). Fused al_s/al_d logits
//            via intra-quad shuffles on the C-fragment.
//   k_edge: per-edge softmax numerators pe[j][h] (coalesced, edge-parallel)
//   k_agg : wave-per-dst-node gather (R7-proven): chunk stash of (u, pe4) in
//           head-transposed LDS, broadcast b128 pair + 4 row gathers per group.
//           Layer 2 fuses h@out_w via shuffle.

#define NBMAX 512   // max dst buckets (dst>>8); N=100K -> 391
#define SCHUNK 4096 // edges per k_bscatter block
#define BCAP 8192   // per-bucket LDS src capacity in k_bfinal (avg 4096)

typedef __attribute__((ext_vector_type(8))) short bf16x8;
typedef __attribute__((ext_vector_type(4))) float f32x4;

__device__ inline unsigned short bf16_rtn(float x) {
    union { float f; unsigned u; } a; a.f = x;
    return (unsigned short)((a.u + 0x7FFFu + ((a.u >> 16) & 1u)) >> 16);
}
__device__ inline float bf16_to_f(unsigned short s) {
    union { unsigned u; float f; } b; b.u = ((unsigned)s) << 16;
    return b.f;
}

__global__ __launch_bounds__(256) void k_zero(int* p, int n) {
    int i = blockIdx.x * 256 + threadIdx.x;
    if (i < n) p[i] = 0;
}

__global__ __launch_bounds__(256) void k_bhist(const int* __restrict__ dst, int* __restrict__ bhist, int e) {
    __shared__ unsigned int h[NBMAX];
    int t = threadIdx.x;
    h[t] = 0;
    h[t + 256] = 0;
    __syncthreads();
    for (int i = blockIdx.x * 256 + t; i < e; i += gridDim.x * 256)
        atomicAdd(&h[dst[i] >> 8], 1u);
    __syncthreads();
    if (h[t]) atomicAdd(&bhist[t], (int)h[t]);
    if (h[t + 256]) atomicAdd(&bhist[t + 256], (int)h[t + 256]);
}

__global__ __launch_bounds__(512) void k_bscan(const int* __restrict__ bhist, int* __restrict__ boffs,
                                               int* __restrict__ bfill, int nb, int e) {
    __shared__ int s[NBMAX];
    int t = threadIdx.x;
    int v = (t < nb) ? bhist[t] : 0;
    s[t] = v;
    __syncthreads();
    for (int o = 1; o < 512; o <<= 1) {
        int add = (t >= o) ? s[t - o] : 0;
        __syncthreads();
        s[t] += add;
        __syncthreads();
    }
    boffs[t] = s[t] - v;  // exclusive
    if (t == 511) boffs[512] = s[511];
    bfill[t] = 0;
}

// Block-local counting sort of a 4096-edge chunk by dst>>8, then streamed
// writes of sorted runs. Packs src (17b) | (dst&255)<<24 into 4B.
__global__ __launch_bounds__(512) void k_bscatter(const int* __restrict__ src, const int* __restrict__ dst,
                                                  const int* __restrict__ boffs, int* __restrict__ bfill,
                                                  unsigned int* __restrict__ edata, int e) {
    __shared__ unsigned int hist[NBMAX];   // counts, then cursor
    __shared__ unsigned int loc[NBMAX];    // local exclusive offsets
    __shared__ int gbase[NBMAX];
    __shared__ unsigned int stmp[NBMAX];
    __shared__ unsigned int sortbuf[SCHUNK];
    __shared__ int posbuf[SCHUNK];
    int t = threadIdx.x;
    int i0 = blockIdx.x * SCHUNK;
    int cnt = min(SCHUNK, e - i0);
    hist[t] = 0;
    __syncthreads();
    for (int j = t; j < cnt; j += 512) atomicAdd(&hist[dst[i0 + j] >> 8], 1u);
    __syncthreads();
    unsigned int v = hist[t];
    stmp[t] = v;
    __syncthreads();
    for (int o = 1; o < 512; o <<= 1) {
        unsigned int add = (t >= o) ? stmp[t - o] : 0;
        __syncthreads();
        stmp[t] += add;
        __syncthreads();
    }
    loc[t] = stmp[t] - v;
    int gb = 0;
    if (v > 0) gb = atomicAdd(&bfill[t], (int)v);  // reserve contiguous run in bucket t
    gbase[t] = boffs[t] + gb - (int)loc[t];
    hist[t] = loc[t];  // cursor
    __syncthreads();
    for (int j = t; j < cnt; j += 512) {
        int d = dst[i0 + j];
        int s = src[i0 + j];
        int b = d >> 8;
        unsigned int p = atomicAdd(&hist[b], 1u);
        sortbuf[p] = (unsigned int)s | ((unsigned int)(d & 255) << 24);
        posbuf[p] = gbase[b] + (int)p;
    }
    __syncthreads();
    for (int j = t; j < cnt; j += 512) edata[posbuf[j]] = sortbuf[j];
}

// One block per bucket: 256-bin counting sort by local dst; coalesced output
// of offs, ssrc (sorted srcs) and sdst (sorted dsts, for k_edge).
__global__ __launch_bounds__(256) void k_bfinal(const unsigned int* __restrict__ edata,
                                                const int* __restrict__ boffs, int* __restrict__ offs,
                                                int* __restrict__ ssrc, int* __restrict__ sdst,
                                                int n, int nb) {
    __shared__ unsigned int hist[256];
    __shared__ unsigned int stmp[256];
    __shared__ unsigned int loc[256];
    __shared__ unsigned int srcbuf[BCAP];
    __shared__ unsigned char dstbuf[BCAP];
    int b = blockIdx.x;
    int t = threadIdx.x;
    int e0 = boffs[b], e1 = boffs[b + 1];
    int cnt = e1 - e0;
    hist[t] = 0;
    __syncthreads();
    for (int j = t; j < cnt; j += 256) atomicAdd(&hist[edata[e0 + j] >> 24], 1u);
    __syncthreads();
    unsigned int v = hist[t];
    stmp[t] = v;
    __syncthreads();
    for (int o = 1; o < 256; o <<= 1) {
        unsigned int add = (t >= o) ? stmp[t - o] : 0;
        __syncthreads();
        stmp[t] += add;
        __syncthreads();
    }
    loc[t] = stmp[t] - v;
    int node = b * 256 + t;
    if (node < n) offs[node] = e0 + (int)loc[t];
    if (b == nb - 1 && t == 0) offs[n] = e1;
    hist[t] = loc[t];  // cursor
    __syncthreads();
    if (cnt <= BCAP) {
        for (int j = t; j < cnt; j += 256) {
            unsigned int p = edata[e0 + j];
            unsigned int pos = atomicAdd(&hist[p >> 24], 1u);
            srcbuf[pos] = p & 0xFFFFFFu;
            dstbuf[pos] = (unsigned char)(p >> 24);
        }
        __syncthreads();
        for (int j = t; j < cnt; j += 256) {
            ssrc[e0 + j] = (int)srcbuf[j];
            sdst[e0 + j] = b * 256 + (int)dstbuf[j];
        }
    } else {  // safety fallback (never hit for Poisson(4096) buckets)
        for (int j = t; j < cnt; j += 256) {
            unsigned int p = edata[e0 + j];
            unsigned int pos = atomicAdd(&hist[p >> 24], 1u);
            ssrc[e0 + (int)pos] = (int)(p & 0xFFFFFFu);
            sdst[e0 + (int)pos] = b * 256 + (int)(p >> 24);
        }
    }
}

// Pack all three layers' W (fp32 [D][64]) into MFMA B-fragment order, hi/lo
// bf16: pack[((ko*64)+n)*8 + j] = bf16(W[ko*8+j][n]). One thread per (ko,n).
__global__ __launch_bounds__(256) void k_wprep(const float* __restrict__ w0, const float* __restrict__ w1,
                                               const float* __restrict__ w2,
                                               unsigned short* __restrict__ p0h, unsigned short* __restrict__ p0l,
                                               unsigned short* __restrict__ p1h, unsigned short* __restrict__ p1l,
                                               unsigned short* __restrict__ p2h, unsigned short* __restrict__ p2l) {
    int g = blockIdx.x * 256 + threadIdx.x;
    const float* W;
    unsigned short *ph, *pl;
    int idx;
    if (g < 1024) { W = w0; ph = p0h; pl = p0l; idx = g; }          // D=128: ko 0..15
    else if (g < 1536) { W = w1; ph = p1h; pl = p1l; idx = g - 1024; }  // D=64: ko 0..7
    else if (g < 2048) { W = w2; ph = p2h; pl = p2l; idx = g - 1536; }
    else return;
    int ko = idx >> 6, nn = idx & 63;
#pragma unroll
    for (int j = 0; j < 8; ++j) {
        float w = W[(size_t)(ko * 8 + j) * 64 + nn];
        unsigned short hb = bf16_rtn(w);
        ph[(size_t)idx * 8 + j] = hb;
        pl[(size_t)idx * 8 + j] = bf16_rtn(w - bf16_to_f(hb));
    }
}

// xh = h @ W via MFMA, fused attention logits. Wave = 16 nodes x 64 cols.
// A frag (verified layout): A[m=lane&15][k=quad*8+j]; B pre-packed to mirror;
// C/D: col=lane&15, row=quad*4+reg. 3 MFMAs per (K-step, N-tile) for the
// hi/lo fp32 emulation. No LDS; B loads are L1-resident (same 16-32KB for
// every block).
template <int D_IN>
__global__ __launch_bounds__(256) void k_mgemm(const float* __restrict__ h,
                                               const unsigned short* __restrict__ wph,
                                               const unsigned short* __restrict__ wpl,
                                               const float* __restrict__ asrc, const float* __restrict__ adst,
                                               float* __restrict__ xh, float* __restrict__ als,
                                               float* __restrict__ ald, int n) {
    int t = threadIdx.x;
    int wv = t >> 6, lane = t & 63;
    int quad = lane >> 4, l16 = lane & 15;
    int m0 = blockIdx.x * 64 + wv * 16;
    int node_a = m0 + l16;
    int mm = min(node_a, n - 1);
    const float* hrow = h + (size_t)mm * D_IN + quad * 8;

    f32x4 acc[4];
#pragma unroll
    for (int i = 0; i < 4; ++i) acc[i] = (f32x4){0.f, 0.f, 0.f, 0.f};

    constexpr int KSTEPS = D_IN / 32;
#pragma unroll
    for (int s = 0; s < KSTEPS; ++s) {
        float4 a0 = *(const float4*)(hrow + s * 32);
        float4 a1 = *(const float4*)(hrow + s * 32 + 4);
        float av[8] = {a0.x, a0.y, a0.z, a0.w, a1.x, a1.y, a1.z, a1.w};
        bf16x8 ahi, alo;
#pragma unroll
        for (int j = 0; j < 8; ++j) {
            unsigned short hb = bf16_rtn(av[j]);
            ahi[j] = (short)hb;
            alo[j] = (short)bf16_rtn(av[j] - bf16_to_f(hb));
        }
        const unsigned short* bbase = wph + ((size_t)((s * 4 + quad) * 64 + l16)) * 8;
        const unsigned short* bbasel = wpl + ((size_t)((s * 4 + quad) * 64 + l16)) * 8;
#pragma unroll
        for (int nt = 0; nt < 4; ++nt) {
            bf16x8 bhi = *(const bf16x8*)(bbase + (size_t)nt * 16 * 8);
            bf16x8 blo = *(const bf16x8*)(bbasel + (size_t)nt * 16 * 8);
            acc[nt] = __builtin_amdgcn_mfma_f32_16x16x32_bf16(ahi, bhi, acc[nt], 0, 0, 0);
            acc[nt] = __builtin_amdgcn_mfma_f32_16x16x32_bf16(ahi, blo, acc[nt], 0, 0, 0);
            acc[nt] = __builtin_amdgcn_mfma_f32_16x16x32_bf16(alo, bhi, acc[nt], 0, 0, 0);
        }
    }
    // epilogue: store xh + fused logits (head == N-tile: 16 cols/head)
#pragma unroll
    for (int nt = 0; nt < 4; ++nt) {
        float as_l = asrc[nt * 16 + l16];
        float ad_l = adst[nt * 16 + l16];
#pragma unroll
        for (int r = 0; r < 4; ++r) {
            int node = m0 + quad * 4 + r;
            float c = acc[nt][r];
            if (node < n) xh[(size_t)node * 64 + nt * 16 + l16] = c;
            float ps = c * as_l, pd = c * ad_l;
            ps += __shfl_xor(ps, 1, 64); pd += __shfl_xor(pd, 1, 64);
            ps += __shfl_xor(ps, 2, 64); pd += __shfl_xor(pd, 2, 64);
            ps += __shfl_xor(ps, 4, 64); pd += __shfl_xor(pd, 4, 64);
            ps += __shfl_xor(ps, 8, 64); pd += __shfl_xor(pd, 8, 64);
            if (l16 == 0 && node < n) {
                als[node * 4 + nt] = ps;
                ald[node * 4 + nt] = pd;
            }
        }
    }
}

__device__ inline float4 lrelu4(float4 v) {
    float4 r;
    r.x = v.x >= 0.f ? v.x : 0.2f * v.x;
    r.y = v.y >= 0.f ? v.y : 0.2f * v.y;
    r.z = v.z >= 0.f ? v.z : 0.2f * v.z;
    r.w = v.w >= 0.f ? v.w : 0.2f * v.w;
    return r;
}

// Edge-parallel softmax numerators: pe[j][h] = exp(lrelu(als[u]+ald[d]) - m[d]),
// m[d] = lrelu(als[d]+ald[d]) (self-logit as per-head shift; single pass,
// algebraically identical to ref's max-subtraction).
__global__ __launch_bounds__(256) void k_edge(const int* __restrict__ ssrc, const int* __restrict__ sdst,
                                              const float* __restrict__ als, const float* __restrict__ ald,
                                              float* __restrict__ pei, int e) {
    int j = blockIdx.x * 256 + threadIdx.x;
    if (j >= e) return;
    int u = ssrc[j], d = sdst[j];
    float4 alu = *(const float4*)(als + 4 * (size_t)u);
    float4 asd = *(const float4*)(als + 4 * (size_t)d);
    float4 add4 = *(const float4*)(ald + 4 * (size_t)d);
    float4 m4 = lrelu4(make_float4(asd.x + add4.x, asd.y + add4.y, asd.z + add4.z, asd.w + add4.w));
    float4 e4 = lrelu4(make_float4(alu.x + add4.x, alu.y + add4.y, alu.z + add4.z, alu.w + add4.w));
    float4 pe;
    pe.x = __expf(e4.x - m4.x);
    pe.y = __expf(e4.y - m4.y);
    pe.z = __expf(e4.z - m4.z);
    pe.w = __expf(e4.w - m4.w);
    *(float4*)(pei + 4 * (size_t)j) = pe;
}

// One wave per destination node; lane = feature column (head = lane>>4).
// Chunk phase: lane=edge loads (u, pe4) coalesced; stash u as row BYTE offset
// and pe transposed [head][edge] in LDS (all 64 lanes write; pad u=v, pe=0).
// Accumulate: per 4 edges, 2x broadcast ds_read_b128 + 4 row gathers + fmacs;
// z accumulated redundantly per lane (no end shuffle-reduce).
__global__ __launch_bounds__(256) void k_agg(const float* __restrict__ xh, const float* __restrict__ pei,
                                             const int* __restrict__ offs, const int* __restrict__ ssrc,
                                             const float* __restrict__ bias, float* __restrict__ hout,
                                             const float* __restrict__ outw, const float* __restrict__ outb,
                                             float* __restrict__ fout, int n) {
    __shared__ int s_u[4][64];
    __shared__ float s_pe[4][4][64];  // [wslot][head][edge]
    int wslot = threadIdx.x >> 6;
    int lane = threadIdx.x & 63;
    int v = (blockIdx.x * 256 + threadIdx.x) >> 6;
    if (v >= n) return;
    int head = lane >> 4;
    int* ub = s_u[wslot];
    float* per = s_pe[wslot][head];      // read row for my head
    float* pew = &s_pe[wslot][0][lane];  // write base, stride 64 per head

    int start = offs[v], end = offs[v + 1];
    const char* xl = (const char*)(xh + lane);      // lane column folded into base
    float acc = *(const float*)(xl + ((size_t)(unsigned)v << 8));  // self, pe=1
    float zsum = 0.f;

    for (int s0 = start; s0 < end; s0 += 64) {
        int cnt = min(64, end - s0);
        bool act = lane < cnt;
        int u = v;
        float4 pe = make_float4(0.f, 0.f, 0.f, 0.f);
        if (act) {
            u = ssrc[s0 + lane];
            pe = *(const float4*)(pei + 4 * (size_t)(s0 + lane));
        }
        ub[lane] = u << 8;   // row byte offset; pad lanes point at v (pe=0)
        pew[0] = pe.x;       // transposed stash: bank stride 64 -> 2-way, free
        pew[64] = pe.y;
        pew[128] = pe.z;
        pew[192] = pe.w;
        // same-wave LDS RAW (in-order DS unit), no barrier needed
        int ng = (cnt + 3) >> 2;
        int g = 0;
        for (; g + 2 <= ng; g += 2) {
            int4 uu0 = *(const int4*)&ub[g * 4];
            int4 uu1 = *(const int4*)&ub[g * 4 + 4];
            float4 pp0 = *(const float4*)&per[g * 4];
            float4 pp1 = *(const float4*)&per[g * 4 + 4];
            float x0 = *(const float*)(xl + (size_t)(unsigned)uu0.x);
            float x1 = *(const float*)(xl + (size_t)(unsigned)uu0.y);
            float x2 = *(const float*)(xl + (size_t)(unsigned)uu0.z);
            float x3 = *(const float*)(xl + (size_t)(unsigned)uu0.w);
            float x4 = *(const float*)(xl + (size_t)(unsigned)uu1.x);
            float x5 = *(const float*)(xl + (size_t)(unsigned)uu1.y);
            float x6 = *(const float*)(xl + (size_t)(unsigned)uu1.z);
            float x7 = *(const float*)(xl + (size_t)(unsigned)uu1.w);
            zsum += pp0.x + pp0.y + pp0.z + pp0.w;
            zsum += pp1.x + pp1.y + pp1.z + pp1.w;
            acc += pp0.x * x0; acc += pp0.y * x1; acc += pp0.z * x2; acc += pp0.w * x3;
            acc += pp1.x * x4; acc += pp1.y * x5; acc += pp1.z * x6; acc += pp1.w * x7;
        }
        for (; g < ng; ++g) {
            int4 uu = *(const int4*)&ub[g * 4];
            float4 pp = *(const float4*)&per[g * 4];
            float x0 = *(const float*)(xl + (size_t)(unsigned)uu.x);
            float x1 = *(const float*)(xl + (size_t)(unsigned)uu.y);
            float x2 = *(const float*)(xl + (size_t)(unsigned)uu.z);
            float x3 = *(const float*)(xl + (size_t)(unsigned)uu.w);
            zsum += pp.x + pp.y + pp.z + pp.w;
            acc += pp.x * x0; acc += pp.y * x1; acc += pp.z * x2; acc += pp.w * x3;
        }
    }
    float z = 1.f + zsum;  // +1 = self edge
    float o = acc / (z + 1e-16f) + bias[lane];
    o = fmaxf(o, 0.f);
    if (outw) {
        float tsum = o * outw[lane];
#pragma unroll
        for (int d = 32; d; d >>= 1) tsum += __shfl_down(tsum, d, 64);
        if (lane == 0) fout[v] = tsum + outb[0];
    } else {
        hout[((size_t)v << 6) + lane] = o;
    }
}

extern "C" void kernel_launch(void* const* d_in, const int* in_sizes, int n_in,
                              void* d_out, int out_size, void* d_ws, size_t ws_size,
                              hipStream_t stream) {
    const float* x = (const float*)d_in[0];
    const int* ei = (const int*)d_in[1];
    const float* w[3] = {(const float*)d_in[2], (const float*)d_in[6], (const float*)d_in[10]};
    const float* as[3] = {(const float*)d_in[3], (const float*)d_in[7], (const float*)d_in[11]};
    const float* ad[3] = {(const float*)d_in[4], (const float*)d_in[8], (const float*)d_in[12]};
    const float* b[3] = {(const float*)d_in[5], (const float*)d_in[9], (const float*)d_in[13]};
    const float* outw = (const float*)d_in[14];
    const float* outb = (const float*)d_in[15];

    const int N = in_sizes[0] / 128;
    const int E = in_sizes[1] / 2;
    const int* src = ei;
    const int* dst = ei + E;
    const int NB = (N + 255) / 256;  // 391 <= NBMAX

    char* ws = (char*)d_ws;
    auto alloc = [&](size_t bytes) -> void* {
        void* p = (void*)ws;
        ws += (bytes + 255) & ~(size_t)255;
        return p;
    };
    int* bhist = (int*)alloc(NBMAX * 4);
    int* boffs = (int*)alloc((NBMAX + 1) * 4);
    int* bfill = (int*)alloc(NBMAX * 4);
    int* offs = (int*)alloc((size_t)(N + 1) * 4);
    int* ssrc = (int*)alloc((size_t)E * 4);
    int* sdst = (int*)alloc((size_t)E * 4);
    float* pei = (float*)alloc((size_t)E * 4 * 4);
    float* xh = (float*)alloc((size_t)N * 64 * 4);
    float* hbuf = (float*)alloc((size_t)N * 64 * 4);
    float* als = (float*)alloc((size_t)N * 4 * 4);
    float* ald = (float*)alloc((size_t)N * 4 * 4);
    unsigned short* p0h = (unsigned short*)alloc(8192 * 2);
    unsigned short* p0l = (unsigned short*)alloc(8192 * 2);
    unsigned short* p1h = (unsigned short*)alloc(4096 * 2);
    unsigned short* p1l = (unsigned short*)alloc(4096 * 2);
    unsigned short* p2h = (unsigned short*)alloc(4096 * 2);
    unsigned short* p2l = (unsigned short*)alloc(4096 * 2);
    // edata (E*4B) aliases xh (N*256B): dead before the first k_mgemm writes xh.
    unsigned int* edata = (unsigned int*)xh;

    k_wprep<<<8, 256, 0, stream>>>(w[0], w[1], w[2], p0h, p0l, p1h, p1l, p2h, p2l);
    k_zero<<<(NBMAX + 255) / 256, 256, 0, stream>>>(bhist, NBMAX);
    k_bhist<<<256, 256, 0, stream>>>(dst, bhist, E);
    k_bscan<<<1, 512, 0, stream>>>(bhist, boffs, bfill, NB, E);
    k_bscatter<<<(E + SCHUNK - 1) / SCHUNK, 512, 0, stream>>>(src, dst, boffs, bfill, edata, E);
    k_bfinal<<<NB, 256, 0, stream>>>(edata, boffs, offs, ssrc, sdst, N, NB);

    const int gblocks = (N + 63) / 64;
    const int ablocks = (N + 3) / 4;
    const int eblocks = (E + 255) / 256;

    k_mgemm<128><<<gblocks, 256, 0, stream>>>(x, p0h, p0l, as[0], ad[0], xh, als, ald, N);
    k_edge<<<eblocks, 256, 0, stream>>>(ssrc, sdst, als, ald, pei, E);
    k_agg<<<ablocks, 256, 0, stream>>>(xh, pei, offs, ssrc, b[0], hbuf, nullptr, nullptr, nullptr, N);
    k_mgemm<64><<<gblocks, 256, 0, stream>>>(hbuf, p1h, p1l, as[1], ad[1], xh, als, ald, N);
    k_edge<<<eblocks, 256, 0, stream>>>(ssrc, sdst, als, ald, pei, E);
    k_agg<<<ablocks, 256, 0, stream>>>(xh, pei, offs, ssrc, b[1], hbuf, nullptr, nullptr, nullptr, N);
    k_mgemm<64><<<gblocks, 256, 0, stream>>>(hbuf, p2h, p2l, as[2], ad[2], xh, als, ald, N);
    k_edge<<<eblocks, 256, 0, stream>>>(ssrc, sdst, als, ald, pei, E);
    k_agg<<<ablocks, 256, 0, stream>>>(xh, pei, offs, ssrc, b[2], nullptr, outw, outb, (float*)d_out, N);
}